// Round 1
// baseline (4244.298 us; speedup 1.0000x reference)
//
#include <hip/hip_runtime.h>
#include <hip/hip_bf16.h>
#include <math.h>

typedef __bf16 bf16;
typedef __bf16 bf16x8 __attribute__((ext_vector_type(8)));
typedef __bf16 bf16x4 __attribute__((ext_vector_type(4)));
typedef float floatx4 __attribute__((ext_vector_type(4)));

#define B_ 2
#define T_ 2048
#define C_ 1024
#define H_ 16
#define HD_ 64

// ---------------------------------------------------------------------------
// Transpose + cast fp32 (K,N) -> bf16 (N,K)
// ---------------------------------------------------------------------------
__global__ void transpose_cast_kernel(const float* __restrict__ in, bf16* __restrict__ out,
                                      int K, int N) {
    __shared__ float tile[32][33];
    int kt = blockIdx.y * 32, nt = blockIdx.x * 32;
    int tx = threadIdx.x, ty = threadIdx.y;  // 32 x 8
    #pragma unroll
    for (int i = 0; i < 32; i += 8)
        tile[ty + i][tx] = in[(size_t)(kt + ty + i) * N + nt + tx];
    __syncthreads();
    #pragma unroll
    for (int i = 0; i < 32; i += 8)
        out[(size_t)(nt + ty + i) * K + kt + tx] = (bf16)tile[tx][ty + i];
}

// ---------------------------------------------------------------------------
// LayerNorm over C=1024. One block (256 threads) per row; 4 floats/thread.
// Writes bf16 (for GEMM A operand) and optionally fp32.
// ---------------------------------------------------------------------------
__global__ __launch_bounds__(256) void ln_kernel(const float* __restrict__ x,
                                                 const float* __restrict__ g,
                                                 const float* __restrict__ b,
                                                 bf16* __restrict__ out_b,
                                                 float* __restrict__ out_f) {
    int row = blockIdx.x;
    int tid = threadIdx.x;
    const float* xr = x + (size_t)row * C_;
    float4 v = ((const float4*)xr)[tid];
    float s  = v.x + v.y + v.z + v.w;
    float ss = v.x * v.x + v.y * v.y + v.z * v.z + v.w * v.w;
    #pragma unroll
    for (int off = 32; off; off >>= 1) {
        s  += __shfl_down(s, off);
        ss += __shfl_down(ss, off);
    }
    __shared__ float red[8];
    int wid = tid >> 6;
    if ((tid & 63) == 0) { red[wid] = s; red[wid + 4] = ss; }
    __syncthreads();
    s  = red[0] + red[1] + red[2] + red[3];
    ss = red[4] + red[5] + red[6] + red[7];
    float mean = s * (1.0f / C_);
    float var  = ss * (1.0f / C_) - mean * mean;
    float rstd = rsqrtf(var + 1e-5f);
    float4 gv = ((const float4*)g)[tid];
    float4 bv = ((const float4*)b)[tid];
    float o0 = (v.x - mean) * rstd * gv.x + bv.x;
    float o1 = (v.y - mean) * rstd * gv.y + bv.y;
    float o2 = (v.z - mean) * rstd * gv.z + bv.z;
    float o3 = (v.w - mean) * rstd * gv.w + bv.w;
    bf16x4 ob = { (bf16)o0, (bf16)o1, (bf16)o2, (bf16)o3 };
    ((bf16x4*)out_b)[(size_t)row * 256 + tid] = ob;
    if (out_f) {
        float4 of; of.x = o0; of.y = o1; of.z = o2; of.w = o3;
        ((float4*)out_f)[(size_t)row * 256 + tid] = of;
    }
}

// ---------------------------------------------------------------------------
// bf16 MFMA GEMM: C[M,N] = A[M,K] @ Bt[N,K]^T (+bias) (+gelu) (+add) -> f32/bf16
// 64x64 block tile, 256 threads = 4 waves, each wave 32x32 via 2x2 of 16x16x32.
// ---------------------------------------------------------------------------
__device__ __forceinline__ float gelu_exact(float v) {
    return 0.5f * v * (1.0f + erff(v * 0.70710678118654752f));
}

__global__ __launch_bounds__(256) void gemm_bt(const bf16* __restrict__ A,
                                               const bf16* __restrict__ Bt,
                                               const float* __restrict__ bias,
                                               const float* __restrict__ add,
                                               float* __restrict__ outF,
                                               bf16* __restrict__ outB,
                                               int M, int N, int K, int do_gelu) {
    __shared__ __align__(16) bf16 As[64 * 72];
    __shared__ __align__(16) bf16 Bs[64 * 72];
    int m0 = blockIdx.y * 64, n0 = blockIdx.x * 64;
    int tid  = threadIdx.x;
    int wid  = tid >> 6, lane = tid & 63;
    int wm = (wid & 1) * 32, wn = (wid >> 1) * 32;
    int lm = lane & 15, lq = lane >> 4;
    int srow = tid >> 3;          // 0..31
    int scol = (tid & 7) * 8;     // 0,8,...,56

    floatx4 acc[2][2];
    #pragma unroll
    for (int i = 0; i < 2; i++)
        #pragma unroll
        for (int j = 0; j < 2; j++) { floatx4 z = {0.f, 0.f, 0.f, 0.f}; acc[i][j] = z; }

    for (int k0 = 0; k0 < K; k0 += 64) {
        bf16x8 a0 = *(const bf16x8*)(A  + (size_t)(m0 + srow)      * K + k0 + scol);
        bf16x8 a1 = *(const bf16x8*)(A  + (size_t)(m0 + srow + 32) * K + k0 + scol);
        bf16x8 b0 = *(const bf16x8*)(Bt + (size_t)(n0 + srow)      * K + k0 + scol);
        bf16x8 b1 = *(const bf16x8*)(Bt + (size_t)(n0 + srow + 32) * K + k0 + scol);
        __syncthreads();   // previous iteration's LDS reads complete
        *(bf16x8*)(As + srow * 72 + scol)        = a0;
        *(bf16x8*)(As + (srow + 32) * 72 + scol) = a1;
        *(bf16x8*)(Bs + srow * 72 + scol)        = b0;
        *(bf16x8*)(Bs + (srow + 32) * 72 + scol) = b1;
        __syncthreads();
        #pragma unroll
        for (int kk = 0; kk < 64; kk += 32) {
            bf16x8 af0 = *(const bf16x8*)(As + (wm + lm)      * 72 + kk + lq * 8);
            bf16x8 af1 = *(const bf16x8*)(As + (wm + 16 + lm) * 72 + kk + lq * 8);
            bf16x8 bf0 = *(const bf16x8*)(Bs + (wn + lm)      * 72 + kk + lq * 8);
            bf16x8 bf1 = *(const bf16x8*)(Bs + (wn + 16 + lm) * 72 + kk + lq * 8);
            acc[0][0] = __builtin_amdgcn_mfma_f32_16x16x32_bf16(af0, bf0, acc[0][0], 0, 0, 0);
            acc[0][1] = __builtin_amdgcn_mfma_f32_16x16x32_bf16(af0, bf1, acc[0][1], 0, 0, 0);
            acc[1][0] = __builtin_amdgcn_mfma_f32_16x16x32_bf16(af1, bf0, acc[1][0], 0, 0, 0);
            acc[1][1] = __builtin_amdgcn_mfma_f32_16x16x32_bf16(af1, bf1, acc[1][1], 0, 0, 0);
        }
    }

    #pragma unroll
    for (int am = 0; am < 2; am++)
        #pragma unroll
        for (int bn = 0; bn < 2; bn++) {
            int mbase = m0 + wm + am * 16 + lq * 4;
            int n     = n0 + wn + bn * 16 + lm;
            float bsn = bias ? bias[n] : 0.0f;
            #pragma unroll
            for (int r = 0; r < 4; r++) {
                int m = mbase + r;
                float v = acc[am][bn][r] + bsn;
                if (do_gelu) v = gelu_exact(v);
                size_t idx = (size_t)m * N + n;
                if (add) v += add[idx];
                if (outF) outF[idx] = v;
                else      outB[idx] = (bf16)v;
            }
        }
}

// ---------------------------------------------------------------------------
// Causal attention, online softmax. One wave per (b,h,q-row).
// qkv bf16 layout: row t of length 3C, head h at offset h*192: [q(64) k(64) v(64)]
// Output o[b,t,h*64+d] bf16.
// ---------------------------------------------------------------------------
__global__ __launch_bounds__(256) void attn_kernel(const bf16* __restrict__ qkv,
                                                   bf16* __restrict__ o) {
    int bh = blockIdx.y;
    int b = bh >> 4, h = bh & 15;
    int wid = threadIdx.x >> 6, lane = threadIdx.x & 63;
    int q = blockIdx.x * 4 + wid;
    const bf16* base = qkv + (size_t)b * T_ * (3 * C_) + h * (3 * HD_);
    const bf16* qrow = base + (size_t)q * (3 * C_);

    float qreg[64];
    #pragma unroll
    for (int i = 0; i < 64; i += 8) {
        bf16x8 t = *(const bf16x8*)(qrow + i);
        #pragma unroll
        for (int j = 0; j < 8; j++) qreg[i + j] = (float)t[j] * 0.125f;  // 1/sqrt(64)
    }

    float m = -1e30f, l = 0.0f, acc = 0.0f;
    for (int k0 = 0; k0 <= q; k0 += 64) {
        int kk = k0 + lane;
        const bf16* krow = base + (size_t)kk * (3 * C_) + HD_;
        float sv = 0.0f;
        #pragma unroll
        for (int i = 0; i < 64; i += 8) {
            bf16x8 t = *(const bf16x8*)(krow + i);
            #pragma unroll
            for (int j = 0; j < 8; j++) sv += qreg[i + j] * (float)t[j];
        }
        float s = (kk <= q) ? sv : -1e30f;

        float cm = s;
        #pragma unroll
        for (int off = 32; off; off >>= 1) cm = fmaxf(cm, __shfl_xor(cm, off));
        float newm = fmaxf(m, cm);
        float p = __expf(s - newm);
        float csum = p;
        #pragma unroll
        for (int off = 32; off; off >>= 1) csum += __shfl_xor(csum, off);
        float alpha = __expf(m - newm);
        l = l * alpha + csum;
        acc *= alpha;
        m = newm;

        const bf16* vbase = base + (size_t)k0 * (3 * C_) + 2 * HD_;
        int jmax = (q - k0 + 1 < 64) ? (q - k0 + 1) : 64;
        for (int j = 0; j < jmax; j++) {
            float pj = __shfl(p, j);
            float vd = (float)vbase[(size_t)j * (3 * C_) + lane];
            acc += pj * vd;
        }
    }
    o[((size_t)b * T_ + q) * C_ + h * HD_ + lane] = (bf16)(acc / l);
}

// ---------------------------------------------------------------------------
extern "C" void kernel_launch(void* const* d_in, const int* in_sizes, int n_in,
                              void* d_out, int out_size, void* d_ws, size_t ws_size,
                              hipStream_t stream) {
    (void)in_sizes; (void)n_in; (void)out_size; (void)ws_size;
    const float* x      = (const float*)d_in[0];
    const float* ln1_g  = (const float*)d_in[1];
    const float* ln1_b  = (const float*)d_in[2];
    const float* ln2_g  = (const float*)d_in[3];
    const float* ln2_b  = (const float*)d_in[4];
    const float* w_in   = (const float*)d_in[5];
    const float* b_in   = (const float*)d_in[6];
    const float* w_out  = (const float*)d_in[7];
    const float* b_out  = (const float*)d_in[8];
    const float* w_fc   = (const float*)d_in[9];
    const float* b_fc   = (const float*)d_in[10];
    const float* w_proj = (const float*)d_in[11];
    const float* b_proj = (const float*)d_in[12];

    char* ws = (char*)d_ws;
    const size_t MB = 1024 * 1024;
    // region plan (96 MiB total, liveness-shared):
    bf16*  w_inT   = (bf16*)(ws + 0);        // 6 MB
    bf16*  w_outT  = (bf16*)(ws + 6 * MB);   // 2 MB
    bf16*  w_fcT   = (bf16*)(ws + 8 * MB);   // 8 MB
    bf16*  w_projT = (bf16*)(ws + 16 * MB);  // 8 MB
    bf16*  qkv     = (bf16*)(ws + 24 * MB);  // 24 MB (shares 32MB region with fc_act)
    bf16*  fc_act  = (bf16*)(ws + 24 * MB);  // 32 MB
    bf16*  o_buf   = (bf16*)(ws + 56 * MB);  // 8 MB (shares with y_b)
    bf16*  y_b     = (bf16*)(ws + 56 * MB);  // 8 MB
    bf16*  h_b     = (bf16*)(ws + 64 * MB);  // 8 MB (shares 16MB region with x1)
    float* x1      = (float*)(ws + 64 * MB); // 16 MB
    float* y_f     = (float*)(ws + 80 * MB); // 16 MB

    const int M = B_ * T_;  // 4096

    dim3 tb(32, 8);
    transpose_cast_kernel<<<dim3(3 * C_ / 32, C_ / 32), tb, 0, stream>>>(w_in,   w_inT,   C_,     3 * C_);
    transpose_cast_kernel<<<dim3(C_ / 32,     C_ / 32), tb, 0, stream>>>(w_out,  w_outT,  C_,     C_);
    transpose_cast_kernel<<<dim3(4 * C_ / 32, C_ / 32), tb, 0, stream>>>(w_fc,   w_fcT,   C_,     4 * C_);
    transpose_cast_kernel<<<dim3(C_ / 32, 4 * C_ / 32), tb, 0, stream>>>(w_proj, w_projT, 4 * C_, C_);

    // h = ln1(x)
    ln_kernel<<<M, 256, 0, stream>>>(x, ln1_g, ln1_b, h_b, nullptr);
    // qkv = h @ w_in + b_in  (bf16 out)
    gemm_bt<<<dim3(3 * C_ / 64, M / 64), 256, 0, stream>>>(h_b, w_inT, b_in, nullptr,
                                                           nullptr, qkv, M, 3 * C_, C_, 0);
    // attention
    attn_kernel<<<dim3(T_ / 4, B_ * H_), 256, 0, stream>>>(qkv, o_buf);
    // x1 = x + o @ w_out + b_out  (f32 out)
    gemm_bt<<<dim3(C_ / 64, M / 64), 256, 0, stream>>>(o_buf, w_outT, b_out, x,
                                                       x1, nullptr, M, C_, C_, 0);
    // y = ln2(x1): bf16 + f32
    ln_kernel<<<M, 256, 0, stream>>>(x1, ln2_g, ln2_b, y_b, y_f);
    // fc = gelu(y @ w_fc + b_fc)  (bf16 out)
    gemm_bt<<<dim3(4 * C_ / 64, M / 64), 256, 0, stream>>>(y_b, w_fcT, b_fc, nullptr,
                                                           nullptr, fc_act, M, 4 * C_, C_, 1);
    // out = y + fc @ w_proj + b_proj  (f32 out)
    gemm_bt<<<dim3(C_ / 64, M / 64), 256, 0, stream>>>(fc_act, w_projT, b_proj, y_f,
                                                       (float*)d_out, nullptr, M, C_, 4 * C_, 0);
}

// Round 2
// 456.765 us; speedup vs baseline: 9.2921x; 9.2921x over previous
//
#include <hip/hip_runtime.h>
#include <hip/hip_bf16.h>
#include <math.h>

typedef __bf16 bf16;
typedef __bf16 bf16x8 __attribute__((ext_vector_type(8)));
typedef __bf16 bf16x4 __attribute__((ext_vector_type(4)));
typedef float floatx4 __attribute__((ext_vector_type(4)));

#define B_ 2
#define T_ 2048
#define C_ 1024
#define H_ 16
#define HD_ 64

// ---------------------------------------------------------------------------
// Transpose + cast fp32 (K,N) -> bf16 (N,K)
// ---------------------------------------------------------------------------
__global__ void transpose_cast_kernel(const float* __restrict__ in, bf16* __restrict__ out,
                                      int K, int N) {
    __shared__ float tile[32][33];
    int kt = blockIdx.y * 32, nt = blockIdx.x * 32;
    int tx = threadIdx.x, ty = threadIdx.y;  // 32 x 8
    #pragma unroll
    for (int i = 0; i < 32; i += 8)
        tile[ty + i][tx] = in[(size_t)(kt + ty + i) * N + nt + tx];
    __syncthreads();
    #pragma unroll
    for (int i = 0; i < 32; i += 8)
        out[(size_t)(nt + ty + i) * K + kt + tx] = (bf16)tile[tx][ty + i];
}

// ---------------------------------------------------------------------------
// LayerNorm over C=1024. One block (256 threads) per row; 4 floats/thread.
// ---------------------------------------------------------------------------
__global__ __launch_bounds__(256) void ln_kernel(const float* __restrict__ x,
                                                 const float* __restrict__ g,
                                                 const float* __restrict__ b,
                                                 bf16* __restrict__ out_b,
                                                 float* __restrict__ out_f) {
    int row = blockIdx.x;
    int tid = threadIdx.x;
    const float* xr = x + (size_t)row * C_;
    float4 v = ((const float4*)xr)[tid];
    float s  = v.x + v.y + v.z + v.w;
    float ss = v.x * v.x + v.y * v.y + v.z * v.z + v.w * v.w;
    #pragma unroll
    for (int off = 32; off; off >>= 1) {
        s  += __shfl_down(s, off);
        ss += __shfl_down(ss, off);
    }
    __shared__ float red[8];
    int wid = tid >> 6;
    if ((tid & 63) == 0) { red[wid] = s; red[wid + 4] = ss; }
    __syncthreads();
    s  = red[0] + red[1] + red[2] + red[3];
    ss = red[4] + red[5] + red[6] + red[7];
    float mean = s * (1.0f / C_);
    float var  = ss * (1.0f / C_) - mean * mean;
    float rstd = rsqrtf(var + 1e-5f);
    float4 gv = ((const float4*)g)[tid];
    float4 bv = ((const float4*)b)[tid];
    float o0 = (v.x - mean) * rstd * gv.x + bv.x;
    float o1 = (v.y - mean) * rstd * gv.y + bv.y;
    float o2 = (v.z - mean) * rstd * gv.z + bv.z;
    float o3 = (v.w - mean) * rstd * gv.w + bv.w;
    bf16x4 ob = { (bf16)o0, (bf16)o1, (bf16)o2, (bf16)o3 };
    ((bf16x4*)out_b)[(size_t)row * 256 + tid] = ob;
    if (out_f) {
        float4 of; of.x = o0; of.y = o1; of.z = o2; of.w = o3;
        ((float4*)out_f)[(size_t)row * 256 + tid] = of;
    }
}

// ---------------------------------------------------------------------------
// bf16 MFMA GEMM: C[M,N] = A[M,K] @ Bt[N,K]^T (+bias) (+gelu) (+add) -> f32/bf16
// 64x64 block tile, 256 threads = 4 waves, each wave 32x32 via 2x2 of 16x16x32.
// ---------------------------------------------------------------------------
__device__ __forceinline__ float gelu_exact(float v) {
    return 0.5f * v * (1.0f + erff(v * 0.70710678118654752f));
}

__global__ __launch_bounds__(256) void gemm_bt(const bf16* __restrict__ A,
                                               const bf16* __restrict__ Bt,
                                               const float* __restrict__ bias,
                                               const float* __restrict__ add,
                                               float* __restrict__ outF,
                                               bf16* __restrict__ outB,
                                               int M, int N, int K, int do_gelu) {
    __shared__ __align__(16) bf16 As[64 * 72];
    __shared__ __align__(16) bf16 Bs[64 * 72];
    int m0 = blockIdx.y * 64, n0 = blockIdx.x * 64;
    int tid  = threadIdx.x;
    int wid  = tid >> 6, lane = tid & 63;
    int wm = (wid & 1) * 32, wn = (wid >> 1) * 32;
    int lm = lane & 15, lq = lane >> 4;
    int srow = tid >> 3;          // 0..31
    int scol = (tid & 7) * 8;     // 0,8,...,56

    floatx4 acc[2][2];
    #pragma unroll
    for (int i = 0; i < 2; i++)
        #pragma unroll
        for (int j = 0; j < 2; j++) { floatx4 z = {0.f, 0.f, 0.f, 0.f}; acc[i][j] = z; }

    for (int k0 = 0; k0 < K; k0 += 64) {
        bf16x8 a0 = *(const bf16x8*)(A  + (size_t)(m0 + srow)      * K + k0 + scol);
        bf16x8 a1 = *(const bf16x8*)(A  + (size_t)(m0 + srow + 32) * K + k0 + scol);
        bf16x8 b0 = *(const bf16x8*)(Bt + (size_t)(n0 + srow)      * K + k0 + scol);
        bf16x8 b1 = *(const bf16x8*)(Bt + (size_t)(n0 + srow + 32) * K + k0 + scol);
        __syncthreads();   // previous iteration's LDS reads complete
        *(bf16x8*)(As + srow * 72 + scol)        = a0;
        *(bf16x8*)(As + (srow + 32) * 72 + scol) = a1;
        *(bf16x8*)(Bs + srow * 72 + scol)        = b0;
        *(bf16x8*)(Bs + (srow + 32) * 72 + scol) = b1;
        __syncthreads();
        #pragma unroll
        for (int kk = 0; kk < 64; kk += 32) {
            bf16x8 af0 = *(const bf16x8*)(As + (wm + lm)      * 72 + kk + lq * 8);
            bf16x8 af1 = *(const bf16x8*)(As + (wm + 16 + lm) * 72 + kk + lq * 8);
            bf16x8 bf0 = *(const bf16x8*)(Bs + (wn + lm)      * 72 + kk + lq * 8);
            bf16x8 bf1 = *(const bf16x8*)(Bs + (wn + 16 + lm) * 72 + kk + lq * 8);
            acc[0][0] = __builtin_amdgcn_mfma_f32_16x16x32_bf16(af0, bf0, acc[0][0], 0, 0, 0);
            acc[0][1] = __builtin_amdgcn_mfma_f32_16x16x32_bf16(af0, bf1, acc[0][1], 0, 0, 0);
            acc[1][0] = __builtin_amdgcn_mfma_f32_16x16x32_bf16(af1, bf0, acc[1][0], 0, 0, 0);
            acc[1][1] = __builtin_amdgcn_mfma_f32_16x16x32_bf16(af1, bf1, acc[1][1], 0, 0, 0);
        }
    }

    #pragma unroll
    for (int am = 0; am < 2; am++)
        #pragma unroll
        for (int bn = 0; bn < 2; bn++) {
            int mbase = m0 + wm + am * 16 + lq * 4;
            int n     = n0 + wn + bn * 16 + lm;
            float bsn = bias ? bias[n] : 0.0f;
            #pragma unroll
            for (int r = 0; r < 4; r++) {
                int m = mbase + r;
                float v = acc[am][bn][r] + bsn;
                if (do_gelu) v = gelu_exact(v);
                size_t idx = (size_t)m * N + n;
                if (add) v += add[idx];
                if (outF) outF[idx] = v;
                else      outB[idx] = (bf16)v;
            }
        }
}

// ---------------------------------------------------------------------------
// Flash attention, MFMA. Block = (b,h,128-q-tile), 4 waves x 32 rows.
// qkv bf16 layout: row t (stride 3C), head h at offset h*192: [q(64) k(64) v(64)]
// K staged in LDS [key][d]; V staged transposed [d][key] with XOR-8-block
// swizzle (breaks the 16-way write conflict of the naive transpose store);
// P round-trips LDS per-wave (C/D layout -> A layout), same swizzle.
// ---------------------------------------------------------------------------
#define QT_ 128
#define KT_ 64

__global__ __launch_bounds__(256) void attn_mfma_kernel(const bf16* __restrict__ qkv,
                                                        bf16* __restrict__ o) {
    int bh = blockIdx.y;
    int b = bh >> 4, h = bh & 15;
    int q0 = blockIdx.x * QT_;
    int tid = threadIdx.x, wid = tid >> 6, lane = tid & 63;
    int wm = wid * 32;
    int lm = lane & 15, quad = lane >> 4;

    const bf16* base = qkv + (size_t)b * T_ * (3 * C_) + h * (3 * HD_);

    __shared__ __align__(16) bf16 Ks[KT_][72];      // K rows [key][d]
    __shared__ __align__(16) bf16 Vt[HD_][72];      // V^T [d][key-swizzled]
    __shared__ __align__(16) bf16 Ps[4][32][72];    // per-wave P [row][col-swizzled]

    // Q fragments in registers for the whole kernel: rows wm..wm+31
    bf16x8 qf[2][2];  // [am][kc]
    #pragma unroll
    for (int am = 0; am < 2; am++)
        #pragma unroll
        for (int kc = 0; kc < 2; kc++) {
            int r = q0 + wm + am * 16 + lm;
            qf[am][kc] = *(const bf16x8*)(base + (size_t)r * (3 * C_) + kc * 32 + quad * 8);
        }

    floatx4 acc_o[2][4];
    #pragma unroll
    for (int am = 0; am < 2; am++)
        #pragma unroll
        for (int dn = 0; dn < 4; dn++) { floatx4 z = {0.f, 0.f, 0.f, 0.f}; acc_o[am][dn] = z; }
    float mst[2][4], lst[2][4];
    #pragma unroll
    for (int am = 0; am < 2; am++)
        #pragma unroll
        for (int reg = 0; reg < 4; reg++) { mst[am][reg] = -1e30f; lst[am][reg] = 0.0f; }

    int srow = tid >> 3;          // 0..31 (key row within half-tile pair handled below)
    int scol = (tid & 7) * 8;     // d base

    int kmax = q0 + QT_;
    for (int k0 = 0; k0 < kmax; k0 += KT_) {
        // ---- stage K and V^T (256 threads cover 64x64: tid>>3 in 0..31 => two halves)
        int kr0 = tid >> 3;               // 0..31
        bf16x8 kv0 = *(const bf16x8*)(base + (size_t)(k0 + kr0)      * (3 * C_) + HD_ + scol);
        bf16x8 kv1 = *(const bf16x8*)(base + (size_t)(k0 + kr0 + 32) * (3 * C_) + HD_ + scol);
        bf16x8 vv0 = *(const bf16x8*)(base + (size_t)(k0 + kr0)      * (3 * C_) + 2 * HD_ + scol);
        bf16x8 vv1 = *(const bf16x8*)(base + (size_t)(k0 + kr0 + 32) * (3 * C_) + 2 * HD_ + scol);
        __syncthreads();   // previous iteration's LDS reads complete
        *(bf16x8*)(&Ks[kr0][scol])      = kv0;
        *(bf16x8*)(&Ks[kr0 + 32][scol]) = kv1;
        {
            int c = scol >> 3;
            int pk0 = (((kr0)       >> 3) ^ c) * 8 + (kr0 & 7);
            int pk1 = (((kr0 + 32)  >> 3) ^ c) * 8 + (kr0 & 7);
            #pragma unroll
            for (int j = 0; j < 8; j++) {
                Vt[scol + j][pk0] = vv0[j];
                Vt[scol + j][pk1] = vv1[j];
            }
        }
        __syncthreads();

        // ---- per-wave: skip tiles entirely above this wave's rows
        if (k0 <= q0 + wm + 31) {
            // S = Q K^T  (rows wm..wm+31, cols 0..63)
            floatx4 s[2][4];
            #pragma unroll
            for (int am = 0; am < 2; am++)
                #pragma unroll
                for (int bn = 0; bn < 4; bn++) { floatx4 z = {0.f, 0.f, 0.f, 0.f}; s[am][bn] = z; }
            #pragma unroll
            for (int kc = 0; kc < 2; kc++) {
                bf16x8 kf[4];
                #pragma unroll
                for (int bn = 0; bn < 4; bn++)
                    kf[bn] = *(const bf16x8*)(&Ks[bn * 16 + lm][kc * 32 + quad * 8]);
                #pragma unroll
                for (int am = 0; am < 2; am++)
                    #pragma unroll
                    for (int bn = 0; bn < 4; bn++)
                        s[am][bn] = __builtin_amdgcn_mfma_f32_16x16x32_bf16(qf[am][kc], kf[bn], s[am][bn], 0, 0, 0);
            }

            int need_mask = (k0 + KT_ - 1) > (q0 + wm);
            // online softmax per row (8 rows/lane: am x reg; 16 lanes share a row)
            #pragma unroll
            for (int am = 0; am < 2; am++) {
                #pragma unroll
                for (int reg = 0; reg < 4; reg++) {
                    int qrow = q0 + wm + am * 16 + quad * 4 + reg;
                    float v[4];
                    #pragma unroll
                    for (int bn = 0; bn < 4; bn++) {
                        float sv = s[am][bn][reg] * 0.125f;   // 1/sqrt(64)
                        int key = k0 + bn * 16 + lm;
                        v[bn] = (!need_mask || key <= qrow) ? sv : -1e30f;
                    }
                    float rm = fmaxf(fmaxf(v[0], v[1]), fmaxf(v[2], v[3]));
                    #pragma unroll
                    for (int off = 8; off; off >>= 1) rm = fmaxf(rm, __shfl_xor(rm, off));
                    float mold = mst[am][reg];
                    float mnew = fmaxf(mold, rm);
                    float alpha = __expf(mold - mnew);
                    mst[am][reg] = mnew;
                    int r = am * 16 + quad * 4 + reg;
                    int sw = (r >> 1) & 7;
                    float ps = 0.f;
                    #pragma unroll
                    for (int bn = 0; bn < 4; bn++) {
                        float p = __expf(v[bn] - mnew);
                        ps += p;
                        int cb = bn * 2 + (lm >> 3);
                        Ps[wid][r][((cb ^ sw) << 3) | (lm & 7)] = (bf16)p;
                    }
                    #pragma unroll
                    for (int off = 8; off; off >>= 1) ps += __shfl_xor(ps, off);
                    lst[am][reg] = lst[am][reg] * alpha + ps;
                    #pragma unroll
                    for (int dn = 0; dn < 4; dn++) acc_o[am][dn][reg] *= alpha;
                }
            }

            // ensure cross-lane LDS writes (Ps) are visible within the wave
            __asm__ volatile("s_waitcnt lgkmcnt(0)" ::: "memory");

            // O += P V  (K-dim = keys)
            #pragma unroll
            for (int kc = 0; kc < 2; kc++) {
                bf16x8 pa[2], vf[4];
                #pragma unroll
                for (int am = 0; am < 2; am++) {
                    int r = am * 16 + lm;
                    int sw = (r >> 1) & 7;
                    pa[am] = *(const bf16x8*)(&Ps[wid][r][((kc * 4 + quad) ^ sw) << 3]);
                }
                #pragma unroll
                for (int dn = 0; dn < 4; dn++) {
                    int d = dn * 16 + lm;
                    int sw = (d >> 3) & 7;
                    vf[dn] = *(const bf16x8*)(&Vt[d][(((kc * 4 + quad) ^ sw) << 3)]);
                }
                #pragma unroll
                for (int am = 0; am < 2; am++)
                    #pragma unroll
                    for (int dn = 0; dn < 4; dn++)
                        acc_o[am][dn] = __builtin_amdgcn_mfma_f32_16x16x32_bf16(pa[am], vf[dn], acc_o[am][dn], 0, 0, 0);
            }
        }
    }

    // normalize + store
    #pragma unroll
    for (int am = 0; am < 2; am++)
        #pragma unroll
        for (int reg = 0; reg < 4; reg++) {
            float inv = 1.0f / lst[am][reg];
            int qrow = q0 + wm + am * 16 + quad * 4 + reg;
            bf16* orow = o + ((size_t)b * T_ + qrow) * C_ + h * HD_;
            #pragma unroll
            for (int dn = 0; dn < 4; dn++)
                orow[dn * 16 + lm] = (bf16)(acc_o[am][dn][reg] * inv);
        }
}

// ---------------------------------------------------------------------------
extern "C" void kernel_launch(void* const* d_in, const int* in_sizes, int n_in,
                              void* d_out, int out_size, void* d_ws, size_t ws_size,
                              hipStream_t stream) {
    (void)in_sizes; (void)n_in; (void)out_size; (void)ws_size;
    const float* x      = (const float*)d_in[0];
    const float* ln1_g  = (const float*)d_in[1];
    const float* ln1_b  = (const float*)d_in[2];
    const float* ln2_g  = (const float*)d_in[3];
    const float* ln2_b  = (const float*)d_in[4];
    const float* w_in   = (const float*)d_in[5];
    const float* b_in   = (const float*)d_in[6];
    const float* w_out  = (const float*)d_in[7];
    const float* b_out  = (const float*)d_in[8];
    const float* w_fc   = (const float*)d_in[9];
    const float* b_fc   = (const float*)d_in[10];
    const float* w_proj = (const float*)d_in[11];
    const float* b_proj = (const float*)d_in[12];

    char* ws = (char*)d_ws;
    const size_t MB = 1024 * 1024;
    bf16*  w_inT   = (bf16*)(ws + 0);        // 6 MB
    bf16*  w_outT  = (bf16*)(ws + 6 * MB);   // 2 MB
    bf16*  w_fcT   = (bf16*)(ws + 8 * MB);   // 8 MB
    bf16*  w_projT = (bf16*)(ws + 16 * MB);  // 8 MB
    bf16*  qkv     = (bf16*)(ws + 24 * MB);  // 24 MB (shares 32MB region with fc_act)
    bf16*  fc_act  = (bf16*)(ws + 24 * MB);  // 32 MB
    bf16*  o_buf   = (bf16*)(ws + 56 * MB);  // 8 MB (shares with y_b)
    bf16*  y_b     = (bf16*)(ws + 56 * MB);  // 8 MB
    bf16*  h_b     = (bf16*)(ws + 64 * MB);  // 8 MB (shares 16MB region with x1)
    float* x1      = (float*)(ws + 64 * MB); // 16 MB
    float* y_f     = (float*)(ws + 80 * MB); // 16 MB

    const int M = B_ * T_;  // 4096

    dim3 tb(32, 8);
    transpose_cast_kernel<<<dim3(3 * C_ / 32, C_ / 32), tb, 0, stream>>>(w_in,   w_inT,   C_,     3 * C_);
    transpose_cast_kernel<<<dim3(C_ / 32,     C_ / 32), tb, 0, stream>>>(w_out,  w_outT,  C_,     C_);
    transpose_cast_kernel<<<dim3(4 * C_ / 32, C_ / 32), tb, 0, stream>>>(w_fc,   w_fcT,   C_,     4 * C_);
    transpose_cast_kernel<<<dim3(C_ / 32, 4 * C_ / 32), tb, 0, stream>>>(w_proj, w_projT, 4 * C_, C_);

    ln_kernel<<<M, 256, 0, stream>>>(x, ln1_g, ln1_b, h_b, nullptr);
    gemm_bt<<<dim3(3 * C_ / 64, M / 64), 256, 0, stream>>>(h_b, w_inT, b_in, nullptr,
                                                           nullptr, qkv, M, 3 * C_, C_, 0);
    attn_mfma_kernel<<<dim3(T_ / QT_, B_ * H_), 256, 0, stream>>>(qkv, o_buf);
    gemm_bt<<<dim3(C_ / 64, M / 64), 256, 0, stream>>>(o_buf, w_outT, b_out, x,
                                                       x1, nullptr, M, C_, C_, 0);
    ln_kernel<<<M, 256, 0, stream>>>(x1, ln2_g, ln2_b, y_b, y_f);
    gemm_bt<<<dim3(4 * C_ / 64, M / 64), 256, 0, stream>>>(y_b, w_fcT, b_fc, nullptr,
                                                           nullptr, fc_act, M, 4 * C_, C_, 1);
    gemm_bt<<<dim3(C_ / 64, M / 64), 256, 0, stream>>>(fc_act, w_projT, b_proj, y_f,
                                                       (float*)d_out, nullptr, M, C_, 4 * C_, 0);
}

// Round 3
// 424.505 us; speedup vs baseline: 9.9982x; 1.0760x over previous
//
#include <hip/hip_runtime.h>
#include <hip/hip_bf16.h>
#include <math.h>

typedef __bf16 bf16;
typedef __bf16 bf16x8 __attribute__((ext_vector_type(8)));
typedef __bf16 bf16x4 __attribute__((ext_vector_type(4)));
typedef float floatx4 __attribute__((ext_vector_type(4)));

#define B_ 2
#define T_ 2048
#define C_ 1024
#define H_ 16
#define HD_ 64

// async global->LDS, 16B per lane; lds dest = uniform base + lane*16
__device__ __forceinline__ void gload_lds16(const bf16* g, bf16* l) {
    __builtin_amdgcn_global_load_lds(
        (const __attribute__((address_space(1))) unsigned int*)(g),
        (__attribute__((address_space(3))) unsigned int*)(l), 16, 0, 0);
}

// ---------------------------------------------------------------------------
// Transpose + cast fp32 (K,N) -> bf16 (N,K)
// ---------------------------------------------------------------------------
__global__ void transpose_cast_kernel(const float* __restrict__ in, bf16* __restrict__ out,
                                      int K, int N) {
    __shared__ float tile[32][33];
    int kt = blockIdx.y * 32, nt = blockIdx.x * 32;
    int tx = threadIdx.x, ty = threadIdx.y;  // 32 x 8
    #pragma unroll
    for (int i = 0; i < 32; i += 8)
        tile[ty + i][tx] = in[(size_t)(kt + ty + i) * N + nt + tx];
    __syncthreads();
    #pragma unroll
    for (int i = 0; i < 32; i += 8)
        out[(size_t)(nt + ty + i) * K + kt + tx] = (bf16)tile[tx][ty + i];
}

// ---------------------------------------------------------------------------
// LayerNorm over C=1024. One block (256 threads) per row; 4 floats/thread.
// ---------------------------------------------------------------------------
__global__ __launch_bounds__(256) void ln_kernel(const float* __restrict__ x,
                                                 const float* __restrict__ g,
                                                 const float* __restrict__ b,
                                                 bf16* __restrict__ out_b,
                                                 float* __restrict__ out_f) {
    int row = blockIdx.x;
    int tid = threadIdx.x;
    const float* xr = x + (size_t)row * C_;
    float4 v = ((const float4*)xr)[tid];
    float s  = v.x + v.y + v.z + v.w;
    float ss = v.x * v.x + v.y * v.y + v.z * v.z + v.w * v.w;
    #pragma unroll
    for (int off = 32; off; off >>= 1) {
        s  += __shfl_down(s, off);
        ss += __shfl_down(ss, off);
    }
    __shared__ float red[8];
    int wid = tid >> 6;
    if ((tid & 63) == 0) { red[wid] = s; red[wid + 4] = ss; }
    __syncthreads();
    s  = red[0] + red[1] + red[2] + red[3];
    ss = red[4] + red[5] + red[6] + red[7];
    float mean = s * (1.0f / C_);
    float var  = ss * (1.0f / C_) - mean * mean;
    float rstd = rsqrtf(var + 1e-5f);
    float4 gv = ((const float4*)g)[tid];
    float4 bv = ((const float4*)b)[tid];
    float o0 = (v.x - mean) * rstd * gv.x + bv.x;
    float o1 = (v.y - mean) * rstd * gv.y + bv.y;
    float o2 = (v.z - mean) * rstd * gv.z + bv.z;
    float o3 = (v.w - mean) * rstd * gv.w + bv.w;
    bf16x4 ob = { (bf16)o0, (bf16)o1, (bf16)o2, (bf16)o3 };
    ((bf16x4*)out_b)[(size_t)row * 256 + tid] = ob;
    if (out_f) {
        float4 of; of.x = o0; of.y = o1; of.z = o2; of.w = o3;
        ((float4*)out_f)[(size_t)row * 256 + tid] = of;
    }
}

// ---------------------------------------------------------------------------
// m97-structure GEMM: C[M,N] = A[M,K] @ Bt[N,K]^T, 128xTN block tile, BK=64,
// unpadded LDS + global_load_lds(16B). 256 thr = 4 waves (2x2), each wave
// 64 x TN/2 via 4 x TN/32 MFMA 16x16x32 tiles.
// MODE: 0 = bias, bf16 out; 1 = bias+gelu, bf16 out; 2 = bias+add, f32 out.
// ---------------------------------------------------------------------------
__device__ __forceinline__ float gelu_exact(float v) {
    return 0.5f * v * (1.0f + erff(v * 0.70710678118654752f));
}

template<int TN, int MODE>
__global__ __launch_bounds__(256) void gemm128(const bf16* __restrict__ A,
                                               const bf16* __restrict__ Bt,
                                               const float* __restrict__ bias,
                                               const float* __restrict__ add,
                                               void* __restrict__ out,
                                               int M, int N, int K) {
    constexpr int BN = TN / 32;           // n-tiles per wave
    __shared__ __align__(16) bf16 As[128 * 64];
    __shared__ __align__(16) bf16 Bs[TN * 64];

    int m0 = blockIdx.y * 128, n0 = blockIdx.x * TN;
    int tid = threadIdx.x;
    int wid = __builtin_amdgcn_readfirstlane(tid >> 6);
    int lane = tid & 63;
    int lm = lane & 15, quad = lane >> 4;
    int wm = (wid & 1) * 64;
    int wn = (wid >> 1) * (TN / 2);
    int lrow = lane >> 3;                 // 0..7
    int lcol = (lane & 7) * 8;

    const bf16* Ablk = A  + (size_t)m0 * K;
    const bf16* Bblk = Bt + (size_t)n0 * K;

    floatx4 acc[4][BN];
    #pragma unroll
    for (int i = 0; i < 4; i++)
        #pragma unroll
        for (int j = 0; j < BN; j++) { floatx4 z = {0.f, 0.f, 0.f, 0.f}; acc[i][j] = z; }

    for (int k0 = 0; k0 < K; k0 += 64) {
        __syncthreads();   // prior iteration's LDS reads complete
        #pragma unroll
        for (int c = 0; c < 4; c++) {
            int row = wid * 32 + c * 8;
            gload_lds16(Ablk + (size_t)(row + lrow) * K + k0 + lcol, As + row * 64);
        }
        #pragma unroll
        for (int c = 0; c < TN / 32; c++) {
            int row = wid * (TN / 4) + c * 8;
            gload_lds16(Bblk + (size_t)(row + lrow) * K + k0 + lcol, Bs + row * 64);
        }
        __syncthreads();   // staged data visible (compiler drains vmcnt)
        #pragma unroll
        for (int kc = 0; kc < 2; kc++) {
            bf16x8 af[4], bfr[BN];
            #pragma unroll
            for (int i = 0; i < 4; i++)
                af[i] = *(const bf16x8*)(As + (wm + i * 16 + lm) * 64 + kc * 32 + quad * 8);
            #pragma unroll
            for (int j = 0; j < BN; j++)
                bfr[j] = *(const bf16x8*)(Bs + (wn + j * 16 + lm) * 64 + kc * 32 + quad * 8);
            #pragma unroll
            for (int i = 0; i < 4; i++)
                #pragma unroll
                for (int j = 0; j < BN; j++)
                    acc[i][j] = __builtin_amdgcn_mfma_f32_16x16x32_bf16(af[i], bfr[j], acc[i][j], 0, 0, 0);
        }
    }

    #pragma unroll
    for (int i = 0; i < 4; i++)
        #pragma unroll
        for (int j = 0; j < BN; j++) {
            int mbase = m0 + wm + i * 16 + quad * 4;
            int n     = n0 + wn + j * 16 + lm;
            float bsn = bias[n];
            #pragma unroll
            for (int r = 0; r < 4; r++) {
                size_t idx = (size_t)(mbase + r) * N + n;
                float v = acc[i][j][r] + bsn;
                if (MODE == 1) v = gelu_exact(v);
                if (MODE == 2) { ((float*)out)[idx] = v + add[idx]; }
                else           { ((bf16*)out)[idx] = (bf16)v; }
            }
        }
}

// ---------------------------------------------------------------------------
// Flash attention, MFMA. Block = (b,h,128-q-tile), 4 waves x 32 rows.
// blockIdx.x = bh (32), blockIdx.y = REVERSED q-tile -> heavy blocks first.
// ---------------------------------------------------------------------------
#define QT_ 128
#define KT_ 64

__global__ __launch_bounds__(256) void attn_mfma_kernel(const bf16* __restrict__ qkv,
                                                        bf16* __restrict__ o) {
    int bh = blockIdx.x;
    int b = bh >> 4, h = bh & 15;
    int q0 = (gridDim.y - 1 - blockIdx.y) * QT_;   // heavy-first
    int tid = threadIdx.x, wid = tid >> 6, lane = tid & 63;
    int wm = wid * 32;
    int lm = lane & 15, quad = lane >> 4;

    const bf16* base = qkv + (size_t)b * T_ * (3 * C_) + h * (3 * HD_);

    __shared__ __align__(16) bf16 Ks[KT_][72];      // K rows [key][d]
    __shared__ __align__(16) bf16 Vt[HD_][72];      // V^T [d][key-swizzled]
    __shared__ __align__(16) bf16 Ps[4][32][72];    // per-wave P [row][col-swizzled]

    bf16x8 qf[2][2];  // [am][kc]
    #pragma unroll
    for (int am = 0; am < 2; am++)
        #pragma unroll
        for (int kc = 0; kc < 2; kc++) {
            int r = q0 + wm + am * 16 + lm;
            qf[am][kc] = *(const bf16x8*)(base + (size_t)r * (3 * C_) + kc * 32 + quad * 8);
        }

    floatx4 acc_o[2][4];
    #pragma unroll
    for (int am = 0; am < 2; am++)
        #pragma unroll
        for (int dn = 0; dn < 4; dn++) { floatx4 z = {0.f, 0.f, 0.f, 0.f}; acc_o[am][dn] = z; }
    float mst[2][4], lst[2][4];
    #pragma unroll
    for (int am = 0; am < 2; am++)
        #pragma unroll
        for (int reg = 0; reg < 4; reg++) { mst[am][reg] = -1e30f; lst[am][reg] = 0.0f; }

    int scol = (tid & 7) * 8;

    int kmax = q0 + QT_;
    for (int k0 = 0; k0 < kmax; k0 += KT_) {
        int kr0 = tid >> 3;               // 0..31
        bf16x8 kv0 = *(const bf16x8*)(base + (size_t)(k0 + kr0)      * (3 * C_) + HD_ + scol);
        bf16x8 kv1 = *(const bf16x8*)(base + (size_t)(k0 + kr0 + 32) * (3 * C_) + HD_ + scol);
        bf16x8 vv0 = *(const bf16x8*)(base + (size_t)(k0 + kr0)      * (3 * C_) + 2 * HD_ + scol);
        bf16x8 vv1 = *(const bf16x8*)(base + (size_t)(k0 + kr0 + 32) * (3 * C_) + 2 * HD_ + scol);
        __syncthreads();
        *(bf16x8*)(&Ks[kr0][scol])      = kv0;
        *(bf16x8*)(&Ks[kr0 + 32][scol]) = kv1;
        {
            int c = scol >> 3;
            int pk0 = (((kr0)       >> 3) ^ c) * 8 + (kr0 & 7);
            int pk1 = (((kr0 + 32)  >> 3) ^ c) * 8 + (kr0 & 7);
            #pragma unroll
            for (int j = 0; j < 8; j++) {
                Vt[scol + j][pk0] = vv0[j];
                Vt[scol + j][pk1] = vv1[j];
            }
        }
        __syncthreads();

        if (k0 <= q0 + wm + 31) {
            floatx4 s[2][4];
            #pragma unroll
            for (int am = 0; am < 2; am++)
                #pragma unroll
                for (int bn = 0; bn < 4; bn++) { floatx4 z = {0.f, 0.f, 0.f, 0.f}; s[am][bn] = z; }
            #pragma unroll
            for (int kc = 0; kc < 2; kc++) {
                bf16x8 kf[4];
                #pragma unroll
                for (int bn = 0; bn < 4; bn++)
                    kf[bn] = *(const bf16x8*)(&Ks[bn * 16 + lm][kc * 32 + quad * 8]);
                #pragma unroll
                for (int am = 0; am < 2; am++)
                    #pragma unroll
                    for (int bn = 0; bn < 4; bn++)
                        s[am][bn] = __builtin_amdgcn_mfma_f32_16x16x32_bf16(qf[am][kc], kf[bn], s[am][bn], 0, 0, 0);
            }

            int need_mask = (k0 + KT_ - 1) > (q0 + wm);
            #pragma unroll
            for (int am = 0; am < 2; am++) {
                #pragma unroll
                for (int reg = 0; reg < 4; reg++) {
                    int qrow = q0 + wm + am * 16 + quad * 4 + reg;
                    float v[4];
                    #pragma unroll
                    for (int bn = 0; bn < 4; bn++) {
                        float sv = s[am][bn][reg] * 0.125f;   // 1/sqrt(64)
                        int key = k0 + bn * 16 + lm;
                        v[bn] = (!need_mask || key <= qrow) ? sv : -1e30f;
                    }
                    float rm = fmaxf(fmaxf(v[0], v[1]), fmaxf(v[2], v[3]));
                    #pragma unroll
                    for (int off = 8; off; off >>= 1) rm = fmaxf(rm, __shfl_xor(rm, off));
                    float mold = mst[am][reg];
                    float mnew = fmaxf(mold, rm);
                    float alpha = __expf(mold - mnew);
                    mst[am][reg] = mnew;
                    int r = am * 16 + quad * 4 + reg;
                    int sw = (r >> 1) & 7;
                    float ps = 0.f;
                    #pragma unroll
                    for (int bn = 0; bn < 4; bn++) {
                        float p = __expf(v[bn] - mnew);
                        ps += p;
                        int cb = bn * 2 + (lm >> 3);
                        Ps[wid][r][((cb ^ sw) << 3) | (lm & 7)] = (bf16)p;
                    }
                    #pragma unroll
                    for (int off = 8; off; off >>= 1) ps += __shfl_xor(ps, off);
                    lst[am][reg] = lst[am][reg] * alpha + ps;
                    #pragma unroll
                    for (int dn = 0; dn < 4; dn++) acc_o[am][dn][reg] *= alpha;
                }
            }

            __asm__ volatile("s_waitcnt lgkmcnt(0)" ::: "memory");

            #pragma unroll
            for (int kc = 0; kc < 2; kc++) {
                bf16x8 pa[2], vf[4];
                #pragma unroll
                for (int am = 0; am < 2; am++) {
                    int r = am * 16 + lm;
                    int sw = (r >> 1) & 7;
                    pa[am] = *(const bf16x8*)(&Ps[wid][r][((kc * 4 + quad) ^ sw) << 3]);
                }
                #pragma unroll
                for (int dn = 0; dn < 4; dn++) {
                    int d = dn * 16 + lm;
                    int sw = (d >> 3) & 7;
                    vf[dn] = *(const bf16x8*)(&Vt[d][(((kc * 4 + quad) ^ sw) << 3)]);
                }
                #pragma unroll
                for (int am = 0; am < 2; am++)
                    #pragma unroll
                    for (int dn = 0; dn < 4; dn++)
                        acc_o[am][dn] = __builtin_amdgcn_mfma_f32_16x16x32_bf16(pa[am], vf[dn], acc_o[am][dn], 0, 0, 0);
            }
        }
    }

    #pragma unroll
    for (int am = 0; am < 2; am++)
        #pragma unroll
        for (int reg = 0; reg < 4; reg++) {
            float inv = 1.0f / lst[am][reg];
            int qrow = q0 + wm + am * 16 + quad * 4 + reg;
            bf16* orow = o + ((size_t)b * T_ + qrow) * C_ + h * HD_;
            #pragma unroll
            for (int dn = 0; dn < 4; dn++)
                orow[dn * 16 + lm] = (bf16)(acc_o[am][dn][reg] * inv);
        }
}

// ---------------------------------------------------------------------------
extern "C" void kernel_launch(void* const* d_in, const int* in_sizes, int n_in,
                              void* d_out, int out_size, void* d_ws, size_t ws_size,
                              hipStream_t stream) {
    (void)in_sizes; (void)n_in; (void)out_size; (void)ws_size;
    const float* x      = (const float*)d_in[0];
    const float* ln1_g  = (const float*)d_in[1];
    const float* ln1_b  = (const float*)d_in[2];
    const float* ln2_g  = (const float*)d_in[3];
    const float* ln2_b  = (const float*)d_in[4];
    const float* w_in   = (const float*)d_in[5];
    const float* b_in   = (const float*)d_in[6];
    const float* w_out  = (const float*)d_in[7];
    const float* b_out  = (const float*)d_in[8];
    const float* w_fc   = (const float*)d_in[9];
    const float* b_fc   = (const float*)d_in[10];
    const float* w_proj = (const float*)d_in[11];
    const float* b_proj = (const float*)d_in[12];

    char* ws = (char*)d_ws;
    const size_t MB = 1024 * 1024;
    bf16*  w_inT   = (bf16*)(ws + 0);        // 6 MB
    bf16*  w_outT  = (bf16*)(ws + 6 * MB);   // 2 MB
    bf16*  w_fcT   = (bf16*)(ws + 8 * MB);   // 8 MB
    bf16*  w_projT = (bf16*)(ws + 16 * MB);  // 8 MB
    bf16*  qkv     = (bf16*)(ws + 24 * MB);  // 24 MB (shares 32MB region with fc_act)
    bf16*  fc_act  = (bf16*)(ws + 24 * MB);  // 32 MB
    bf16*  o_buf   = (bf16*)(ws + 56 * MB);  // 8 MB (shares with y_b)
    bf16*  y_b     = (bf16*)(ws + 56 * MB);  // 8 MB
    bf16*  h_b     = (bf16*)(ws + 64 * MB);  // 8 MB (shares 16MB region with x1)
    float* x1      = (float*)(ws + 64 * MB); // 16 MB
    float* y_f     = (float*)(ws + 80 * MB); // 16 MB

    const int M = B_ * T_;  // 4096

    dim3 tb(32, 8);
    transpose_cast_kernel<<<dim3(3 * C_ / 32, C_ / 32), tb, 0, stream>>>(w_in,   w_inT,   C_,     3 * C_);
    transpose_cast_kernel<<<dim3(C_ / 32,     C_ / 32), tb, 0, stream>>>(w_out,  w_outT,  C_,     C_);
    transpose_cast_kernel<<<dim3(4 * C_ / 32, C_ / 32), tb, 0, stream>>>(w_fc,   w_fcT,   C_,     4 * C_);
    transpose_cast_kernel<<<dim3(C_ / 32, 4 * C_ / 32), tb, 0, stream>>>(w_proj, w_projT, 4 * C_, C_);

    ln_kernel<<<M, 256, 0, stream>>>(x, ln1_g, ln1_b, h_b, nullptr);
    gemm128<128, 0><<<dim3(3 * C_ / 128, M / 128), 256, 0, stream>>>(h_b, w_inT, b_in, nullptr,
                                                                     qkv, M, 3 * C_, C_);
    attn_mfma_kernel<<<dim3(B_ * H_, T_ / QT_), 256, 0, stream>>>(qkv, o_buf);
    gemm128<64, 2><<<dim3(C_ / 64, M / 128), 256, 0, stream>>>(o_buf, w_outT, b_out, x,
                                                               x1, M, C_, C_);
    ln_kernel<<<M, 256, 0, stream>>>(x1, ln2_g, ln2_b, y_b, y_f);
    gemm128<128, 1><<<dim3(4 * C_ / 128, M / 128), 256, 0, stream>>>(y_b, w_fcT, b_fc, nullptr,
                                                                     fc_act, M, 4 * C_, C_);
    gemm128<64, 2><<<dim3(C_ / 64, M / 128), 256, 0, stream>>>(fc_act, w_projT, b_proj, y_f,
                                                               (float*)d_out, M, C_, 4 * C_);
}

// Round 4
// 391.779 us; speedup vs baseline: 10.8334x; 1.0835x over previous
//
#include <hip/hip_runtime.h>
#include <hip/hip_bf16.h>
#include <math.h>

typedef __bf16 bf16;
typedef __bf16 bf16x8 __attribute__((ext_vector_type(8)));
typedef __bf16 bf16x4 __attribute__((ext_vector_type(4)));
typedef float floatx4 __attribute__((ext_vector_type(4)));

#define B_ 2
#define T_ 2048
#define C_ 1024
#define H_ 16
#define HD_ 64

// async global->LDS, 16B per lane; lds dest = uniform base + lane*16
__device__ __forceinline__ void gload_lds16(const bf16* g, bf16* l) {
    __builtin_amdgcn_global_load_lds(
        (const __attribute__((address_space(1))) unsigned int*)(g),
        (__attribute__((address_space(3))) unsigned int*)(l), 16, 0, 0);
}

// ---------------------------------------------------------------------------
// Transpose + cast fp32 (K,N) -> bf16 (N,K)
// ---------------------------------------------------------------------------
__global__ void transpose_cast_kernel(const float* __restrict__ in, bf16* __restrict__ out,
                                      int K, int N) {
    __shared__ float tile[32][33];
    int kt = blockIdx.y * 32, nt = blockIdx.x * 32;
    int tx = threadIdx.x, ty = threadIdx.y;  // 32 x 8
    #pragma unroll
    for (int i = 0; i < 32; i += 8)
        tile[ty + i][tx] = in[(size_t)(kt + ty + i) * N + nt + tx];
    __syncthreads();
    #pragma unroll
    for (int i = 0; i < 32; i += 8)
        out[(size_t)(nt + ty + i) * K + kt + tx] = (bf16)tile[tx][ty + i];
}

// ---------------------------------------------------------------------------
// LayerNorm over C=1024. One block (256 threads) per row; 4 floats/thread.
// ---------------------------------------------------------------------------
__global__ __launch_bounds__(256) void ln_kernel(const float* __restrict__ x,
                                                 const float* __restrict__ g,
                                                 const float* __restrict__ b,
                                                 bf16* __restrict__ out_b,
                                                 float* __restrict__ out_f) {
    int row = blockIdx.x;
    int tid = threadIdx.x;
    const float* xr = x + (size_t)row * C_;
    float4 v = ((const float4*)xr)[tid];
    float s  = v.x + v.y + v.z + v.w;
    float ss = v.x * v.x + v.y * v.y + v.z * v.z + v.w * v.w;
    #pragma unroll
    for (int off = 32; off; off >>= 1) {
        s  += __shfl_down(s, off);
        ss += __shfl_down(ss, off);
    }
    __shared__ float red[8];
    int wid = tid >> 6;
    if ((tid & 63) == 0) { red[wid] = s; red[wid + 4] = ss; }
    __syncthreads();
    s  = red[0] + red[1] + red[2] + red[3];
    ss = red[4] + red[5] + red[6] + red[7];
    float mean = s * (1.0f / C_);
    float var  = ss * (1.0f / C_) - mean * mean;
    float rstd = rsqrtf(var + 1e-5f);
    float4 gv = ((const float4*)g)[tid];
    float4 bv = ((const float4*)b)[tid];
    float o0 = (v.x - mean) * rstd * gv.x + bv.x;
    float o1 = (v.y - mean) * rstd * gv.y + bv.y;
    float o2 = (v.z - mean) * rstd * gv.z + bv.z;
    float o3 = (v.w - mean) * rstd * gv.w + bv.w;
    bf16x4 ob = { (bf16)o0, (bf16)o1, (bf16)o2, (bf16)o3 };
    ((bf16x4*)out_b)[(size_t)row * 256 + tid] = ob;
    if (out_f) {
        float4 of; of.x = o0; of.y = o1; of.z = o2; of.w = o3;
        ((float4*)out_f)[(size_t)row * 256 + tid] = of;
    }
}

// ---------------------------------------------------------------------------
// m97-structure GEMM: C[M,N] = A[M,K] @ Bt[N,K]^T, 128xTN block tile, BK=64,
// unpadded LDS + global_load_lds(16B).
// MODE: 0 = bias, bf16 out; 1 = bias+gelu, bf16 out; 2 = bias+add, f32 out.
// ---------------------------------------------------------------------------
__device__ __forceinline__ float gelu_exact(float v) {
    return 0.5f * v * (1.0f + erff(v * 0.70710678118654752f));
}

template<int TN, int MODE>
__global__ __launch_bounds__(256) void gemm128(const bf16* __restrict__ A,
                                               const bf16* __restrict__ Bt,
                                               const float* __restrict__ bias,
                                               const float* __restrict__ add,
                                               void* __restrict__ out,
                                               int M, int N, int K) {
    constexpr int BN = TN / 32;           // n-tiles per wave
    __shared__ __align__(16) bf16 As[128 * 64];
    __shared__ __align__(16) bf16 Bs[TN * 64];

    int m0 = blockIdx.y * 128, n0 = blockIdx.x * TN;
    int tid = threadIdx.x;
    int wid = __builtin_amdgcn_readfirstlane(tid >> 6);
    int lane = tid & 63;
    int lm = lane & 15, quad = lane >> 4;
    int wm = (wid & 1) * 64;
    int wn = (wid >> 1) * (TN / 2);
    int lrow = lane >> 3;                 // 0..7
    int lcol = (lane & 7) * 8;

    const bf16* Ablk = A  + (size_t)m0 * K;
    const bf16* Bblk = Bt + (size_t)n0 * K;

    floatx4 acc[4][BN];
    #pragma unroll
    for (int i = 0; i < 4; i++)
        #pragma unroll
        for (int j = 0; j < BN; j++) { floatx4 z = {0.f, 0.f, 0.f, 0.f}; acc[i][j] = z; }

    for (int k0 = 0; k0 < K; k0 += 64) {
        __syncthreads();   // prior iteration's LDS reads complete
        #pragma unroll
        for (int c = 0; c < 4; c++) {
            int row = wid * 32 + c * 8;
            gload_lds16(Ablk + (size_t)(row + lrow) * K + k0 + lcol, As + row * 64);
        }
        #pragma unroll
        for (int c = 0; c < TN / 32; c++) {
            int row = wid * (TN / 4) + c * 8;
            gload_lds16(Bblk + (size_t)(row + lrow) * K + k0 + lcol, Bs + row * 64);
        }
        __syncthreads();   // staged data visible (compiler drains vmcnt)
        #pragma unroll
        for (int kc = 0; kc < 2; kc++) {
            bf16x8 af[4], bfr[BN];
            #pragma unroll
            for (int i = 0; i < 4; i++)
                af[i] = *(const bf16x8*)(As + (wm + i * 16 + lm) * 64 + kc * 32 + quad * 8);
            #pragma unroll
            for (int j = 0; j < BN; j++)
                bfr[j] = *(const bf16x8*)(Bs + (wn + j * 16 + lm) * 64 + kc * 32 + quad * 8);
            #pragma unroll
            for (int i = 0; i < 4; i++)
                #pragma unroll
                for (int j = 0; j < BN; j++)
                    acc[i][j] = __builtin_amdgcn_mfma_f32_16x16x32_bf16(af[i], bfr[j], acc[i][j], 0, 0, 0);
        }
    }

    #pragma unroll
    for (int i = 0; i < 4; i++)
        #pragma unroll
        for (int j = 0; j < BN; j++) {
            int mbase = m0 + wm + i * 16 + quad * 4;
            int n     = n0 + wn + j * 16 + lm;
            float bsn = bias[n];
            #pragma unroll
            for (int r = 0; r < 4; r++) {
                size_t idx = (size_t)(mbase + r) * N + n;
                float v = acc[i][j][r] + bsn;
                if (MODE == 1) v = gelu_exact(v);
                if (MODE == 2) { ((float*)out)[idx] = v + add[idx]; }
                else           { ((bf16*)out)[idx] = (bf16)v; }
            }
        }
}

// ---------------------------------------------------------------------------
// Flash attention, MFMA, S^T formulation.
// S^T = mfma(K-frag, Q-frag): C-layout col(lm)=q-row, rows(quad*4+reg)=keys.
// Softmax per-lane over 16 in-register keys + 2 shfl_xor (cross-quad).
// P is key-contiguous per lane -> vectorized b64 LDS stores (xor-swizzled),
// read back as b128 A-frags for PV. alpha/l broadcast to C-layout rows via
// 4 bpermutes per subtile. Removes 32 b16 scatter + 56 ds_swizzle per tile.
// ---------------------------------------------------------------------------
#define QT_ 128
#define KT_ 64

__global__ __launch_bounds__(256) void attn_mfma_kernel(const bf16* __restrict__ qkv,
                                                        bf16* __restrict__ o) {
    int bh = blockIdx.x;
    int b = bh >> 4, h = bh & 15;
    int q0 = (gridDim.y - 1 - blockIdx.y) * QT_;   // heavy-first
    int tid = threadIdx.x, wid = tid >> 6, lane = tid & 63;
    int wm = wid * 32;
    int lm = lane & 15, quad = lane >> 4;
    int sw = lm & 7;

    const bf16* base = qkv + (size_t)b * T_ * (3 * C_) + h * (3 * HD_);

    __shared__ __align__(16) bf16 Ks[KT_][72];      // K rows [key][d]
    __shared__ __align__(16) bf16 Vt[HD_][72];      // V^T [d][key-swizzled]
    __shared__ __align__(16) bf16 PsT[4][32][64];   // per-wave P [qrow][key-swizzled]

    bf16x8 qf[2][2];  // [am][kc]  (B-operand: lane lm = q-row)
    #pragma unroll
    for (int am = 0; am < 2; am++)
        #pragma unroll
        for (int kc = 0; kc < 2; kc++) {
            int r = q0 + wm + am * 16 + lm;
            qf[am][kc] = *(const bf16x8*)(base + (size_t)r * (3 * C_) + kc * 32 + quad * 8);
        }

    floatx4 acc_o[2][4];
    #pragma unroll
    for (int am = 0; am < 2; am++)
        #pragma unroll
        for (int dn = 0; dn < 4; dn++) { floatx4 z = {0.f, 0.f, 0.f, 0.f}; acc_o[am][dn] = z; }
    float mst[2] = { -1e30f, -1e30f };
    float lst[2] = { 0.0f, 0.0f };

    int scol = (tid & 7) * 8;

    int kmax = q0 + QT_;
    for (int k0 = 0; k0 < kmax; k0 += KT_) {
        int kr0 = tid >> 3;               // 0..31
        bf16x8 kv0 = *(const bf16x8*)(base + (size_t)(k0 + kr0)      * (3 * C_) + HD_ + scol);
        bf16x8 kv1 = *(const bf16x8*)(base + (size_t)(k0 + kr0 + 32) * (3 * C_) + HD_ + scol);
        bf16x8 vv0 = *(const bf16x8*)(base + (size_t)(k0 + kr0)      * (3 * C_) + 2 * HD_ + scol);
        bf16x8 vv1 = *(const bf16x8*)(base + (size_t)(k0 + kr0 + 32) * (3 * C_) + 2 * HD_ + scol);
        __syncthreads();
        *(bf16x8*)(&Ks[kr0][scol])      = kv0;
        *(bf16x8*)(&Ks[kr0 + 32][scol]) = kv1;
        {
            int c = scol >> 3;
            int pk0 = (((kr0)       >> 3) ^ c) * 8 + (kr0 & 7);
            int pk1 = (((kr0 + 32)  >> 3) ^ c) * 8 + (kr0 & 7);
            #pragma unroll
            for (int j = 0; j < 8; j++) {
                Vt[scol + j][pk0] = vv0[j];
                Vt[scol + j][pk1] = vv1[j];
            }
        }
        __syncthreads();

        if (k0 <= q0 + wm + 31) {
            // S^T: rows = keys (4 tiles), cols = q-rows (2 tiles)
            floatx4 st[4][2];
            #pragma unroll
            for (int bn = 0; bn < 4; bn++)
                #pragma unroll
                for (int am = 0; am < 2; am++) { floatx4 z = {0.f, 0.f, 0.f, 0.f}; st[bn][am] = z; }
            #pragma unroll
            for (int kc = 0; kc < 2; kc++) {
                bf16x8 kf[4];
                #pragma unroll
                for (int bn = 0; bn < 4; bn++)
                    kf[bn] = *(const bf16x8*)(&Ks[bn * 16 + lm][kc * 32 + quad * 8]);
                #pragma unroll
                for (int bn = 0; bn < 4; bn++)
                    #pragma unroll
                    for (int am = 0; am < 2; am++)
                        st[bn][am] = __builtin_amdgcn_mfma_f32_16x16x32_bf16(kf[bn], qf[am][kc], st[bn][am], 0, 0, 0);
            }

            float alpha_s[2];
            #pragma unroll
            for (int am = 0; am < 2; am++) {
                int gq = q0 + wm + am * 16 + lm;           // this lane's q-row
                int need_mask = (k0 + KT_ - 1) > (q0 + wm + am * 16);
                float vv[4][4];
                float rm = -1e30f;
                #pragma unroll
                for (int bn = 0; bn < 4; bn++)
                    #pragma unroll
                    for (int r = 0; r < 4; r++) {
                        float sv = st[bn][am][r] * 0.125f;  // 1/sqrt(64)
                        int key = k0 + bn * 16 + quad * 4 + r;
                        sv = (!need_mask || key <= gq) ? sv : -1e30f;
                        vv[bn][r] = sv;
                        rm = fmaxf(rm, sv);
                    }
                rm = fmaxf(rm, __shfl_xor(rm, 16));
                rm = fmaxf(rm, __shfl_xor(rm, 32));
                float mold = mst[am];
                float mnew = fmaxf(mold, rm);
                float alpha = __expf(mold - mnew);
                mst[am] = mnew;
                float ps = 0.f;
                #pragma unroll
                for (int bn = 0; bn < 4; bn++) {
                    float p0 = __expf(vv[bn][0] - mnew);
                    float p1 = __expf(vv[bn][1] - mnew);
                    float p2 = __expf(vv[bn][2] - mnew);
                    float p3 = __expf(vv[bn][3] - mnew);
                    ps += (p0 + p1) + (p2 + p3);
                    bf16x4 pk = { (bf16)p0, (bf16)p1, (bf16)p2, (bf16)p3 };
                    int kb = bn * 2 + (quad >> 1);
                    int col = ((kb ^ sw) << 3) + (quad & 1) * 4;
                    *(bf16x4*)(&PsT[wid][am * 16 + lm][col]) = pk;
                }
                ps += __shfl_xor(ps, 16);
                ps += __shfl_xor(ps, 32);
                lst[am] = lst[am] * alpha + ps;
                alpha_s[am] = alpha;
            }

            // rescale O accumulators (C-layout rows quad*4+reg <- alpha at lane lm=row)
            #pragma unroll
            for (int am = 0; am < 2; am++)
                #pragma unroll
                for (int r = 0; r < 4; r++) {
                    float ar = __shfl(alpha_s[am], quad * 4 + r);
                    #pragma unroll
                    for (int dn = 0; dn < 4; dn++) acc_o[am][dn][r] *= ar;
                }

            __asm__ volatile("s_waitcnt lgkmcnt(0)" ::: "memory");

            // O += P V
            #pragma unroll
            for (int kc = 0; kc < 2; kc++) {
                bf16x8 pa[2], vfr[4];
                #pragma unroll
                for (int am = 0; am < 2; am++)
                    pa[am] = *(const bf16x8*)(&PsT[wid][am * 16 + lm][((kc * 4 + quad) ^ sw) << 3]);
                #pragma unroll
                for (int dn = 0; dn < 4; dn++) {
                    int d = dn * 16 + lm;
                    int swd = (d >> 3) & 7;
                    vfr[dn] = *(const bf16x8*)(&Vt[d][(((kc * 4 + quad) ^ swd) << 3)]);
                }
                #pragma unroll
                for (int am = 0; am < 2; am++)
                    #pragma unroll
                    for (int dn = 0; dn < 4; dn++)
                        acc_o[am][dn] = __builtin_amdgcn_mfma_f32_16x16x32_bf16(pa[am], vfr[dn], acc_o[am][dn], 0, 0, 0);
            }
        }
    }

    // normalize + store (1/l broadcast lane lm=row -> C-layout rows)
    #pragma unroll
    for (int am = 0; am < 2; am++) {
        float il = 1.0f / lst[am];
        #pragma unroll
        for (int r = 0; r < 4; r++) {
            float ir = __shfl(il, quad * 4 + r);
            int qrow = q0 + wm + am * 16 + quad * 4 + r;
            bf16* orow = o + ((size_t)b * T_ + qrow) * C_ + h * HD_;
            #pragma unroll
            for (int dn = 0; dn < 4; dn++)
                orow[dn * 16 + lm] = (bf16)(acc_o[am][dn][r] * ir);
        }
    }
}

// ---------------------------------------------------------------------------
extern "C" void kernel_launch(void* const* d_in, const int* in_sizes, int n_in,
                              void* d_out, int out_size, void* d_ws, size_t ws_size,
                              hipStream_t stream) {
    (void)in_sizes; (void)n_in; (void)out_size; (void)ws_size;
    const float* x      = (const float*)d_in[0];
    const float* ln1_g  = (const float*)d_in[1];
    const float* ln1_b  = (const float*)d_in[2];
    const float* ln2_g  = (const float*)d_in[3];
    const float* ln2_b  = (const float*)d_in[4];
    const float* w_in   = (const float*)d_in[5];
    const float* b_in   = (const float*)d_in[6];
    const float* w_out  = (const float*)d_in[7];
    const float* b_out  = (const float*)d_in[8];
    const float* w_fc   = (const float*)d_in[9];
    const float* b_fc   = (const float*)d_in[10];
    const float* w_proj = (const float*)d_in[11];
    const float* b_proj = (const float*)d_in[12];

    char* ws = (char*)d_ws;
    const size_t MB = 1024 * 1024;
    bf16*  w_inT   = (bf16*)(ws + 0);        // 6 MB
    bf16*  w_outT  = (bf16*)(ws + 6 * MB);   // 2 MB
    bf16*  w_fcT   = (bf16*)(ws + 8 * MB);   // 8 MB
    bf16*  w_projT = (bf16*)(ws + 16 * MB);  // 8 MB
    bf16*  qkv     = (bf16*)(ws + 24 * MB);  // 24 MB (shares 32MB region with fc_act)
    bf16*  fc_act  = (bf16*)(ws + 24 * MB);  // 32 MB
    bf16*  o_buf   = (bf16*)(ws + 56 * MB);  // 8 MB (shares with y_b)
    bf16*  y_b     = (bf16*)(ws + 56 * MB);  // 8 MB
    bf16*  h_b     = (bf16*)(ws + 64 * MB);  // 8 MB (shares 16MB region with x1)
    float* x1      = (float*)(ws + 64 * MB); // 16 MB
    float* y_f     = (float*)(ws + 80 * MB); // 16 MB

    const int M = B_ * T_;  // 4096

    dim3 tb(32, 8);
    transpose_cast_kernel<<<dim3(3 * C_ / 32, C_ / 32), tb, 0, stream>>>(w_in,   w_inT,   C_,     3 * C_);
    transpose_cast_kernel<<<dim3(C_ / 32,     C_ / 32), tb, 0, stream>>>(w_out,  w_outT,  C_,     C_);
    transpose_cast_kernel<<<dim3(4 * C_ / 32, C_ / 32), tb, 0, stream>>>(w_fc,   w_fcT,   C_,     4 * C_);
    transpose_cast_kernel<<<dim3(C_ / 32, 4 * C_ / 32), tb, 0, stream>>>(w_proj, w_projT, 4 * C_, C_);

    ln_kernel<<<M, 256, 0, stream>>>(x, ln1_g, ln1_b, h_b, nullptr);
    gemm128<128, 0><<<dim3(3 * C_ / 128, M / 128), 256, 0, stream>>>(h_b, w_inT, b_in, nullptr,
                                                                     qkv, M, 3 * C_, C_);
    attn_mfma_kernel<<<dim3(B_ * H_, T_ / QT_), 256, 0, stream>>>(qkv, o_buf);
    gemm128<64, 2><<<dim3(C_ / 64, M / 128), 256, 0, stream>>>(o_buf, w_outT, b_out, x,
                                                               x1, M, C_, C_);
    ln_kernel<<<M, 256, 0, stream>>>(x1, ln2_g, ln2_b, y_b, y_f);
    gemm128<128, 1><<<dim3(4 * C_ / 128, M / 128), 256, 0, stream>>>(y_b, w_fcT, b_fc, nullptr,
                                                                     fc_act, M, 4 * C_, C_);
    gemm128<64, 2><<<dim3(C_ / 64, M / 128), 256, 0, stream>>>(fc_act, w_projT, b_proj, y_f,
                                                               (float*)d_out, M, C_, 4 * C_);
}